// Round 10
// baseline (163.662 us; speedup 1.0000x reference)
//
#include <hip/hip_runtime.h>
#include <hip/hip_bf16.h>

#define B_  8
#define H_  512
#define L_  2048
#define D2_ 32
#define NC_ 64
#define LC_ 32    // L_/NC_
#define EP  36    // E_lds row pitch in u32 (16B-aligned rows)

typedef __attribute__((ext_vector_type(8))) short short8;     // 8 bf16 (4 VGPRs)
typedef __attribute__((ext_vector_type(8))) _Float16 half8;   // 8 fp16 (4 VGPRs)
typedef __attribute__((ext_vector_type(2))) _Float16 half2v;  // packed fp16 (v_pk_*)
typedef __attribute__((ext_vector_type(4))) float float4v;    // 4 fp32 acc

__device__ __forceinline__ half2v pk_fma16(half2v a, half2v b, half2v c) {
    return __builtin_elementwise_fma(a, b, c);
}

// tanh-form GELU: max |err| vs exact ~3e-4, far below bf16 y-storage ulp.
__device__ __forceinline__ float gelu_fast(float x) {
    float q = x * fmaf(0.044715f, x * x, 1.0f);
    float s = __expf(-1.5957691216057308f * q);   // e^{-2*0.79788456*q}
    return __fdividef(x, 1.0f + s);               // x * sigmoid(2w)
}

__device__ __forceinline__ unsigned pack_bf16x2(float x, float y) {
    __hip_bfloat162 p = __float22bfloat162_rn(make_float2(x, y));
    return *(unsigned*)&p;
}
__device__ __forceinline__ float2 unpack_bf16x2(unsigned v) {
    __hip_bfloat162 p = *(__hip_bfloat162*)&v;
    return __bfloat1622float2(p);
}
__device__ __forceinline__ unsigned pack_f16x2(float x, float y) {
    auto v = __builtin_amdgcn_cvt_pkrtz(x, y);    // v_cvt_pkrtz_f16_f32
    return *(unsigned*)&v;
}

__device__ __forceinline__ void load_lds16(const void* g, void* l) {
    __builtin_amdgcn_global_load_lds((const __attribute__((address_space(1))) unsigned int*)g,
                                     (__attribute__((address_space(3))) unsigned int*)l, 16, 0, 0);
}

// ---------------- fkprep: params + fk (f,k0) + MFMA operands + W-cast, 1 block/h ----
__global__ __launch_bounds__(256) void fkprep_kernel(
        const float* __restrict__ a, const float* __restrict__ th,
        const float* __restrict__ bb, const float* __restrict__ cc,
        const float* __restrict__ x0, const float* __restrict__ W,
        __hip_bfloat16* __restrict__ Wb, unsigned* __restrict__ FKf,
        _Float16* __restrict__ AB, _Float16* __restrict__ CB,
        _Float16* __restrict__ WPh) {
    __shared__ float avs[32], tvs[32], qds[32], gxs[32], f_lds[32];
    __shared__ unsigned fk_all[32 * 64];     // [i][lc]
    int h = blockIdx.x;
    int t = threadIdx.x;
    const float T = 1.0f / (float)(L_ - 1);
    // W row cast (independent of everything else)
    Wb[(size_t)h * 512 + t]       = __float2bfloat16(W[(size_t)h * 512 + t]);
    Wb[(size_t)h * 512 + t + 256] = __float2bfloat16(W[(size_t)h * 512 + t + 256]);
    // phase 0: per-d params + WPh
    if (t < 32) {
        int d = t;
        float av = -fabsf(a[h * D2_ + d]);
        float tv = th[h * D2_ + d];
        avs[d] = av; tvs[d] = tv;
        qds[d] = bb[h * D2_ + d] * cc[h * D2_ + d];
        gxs[d] = 2.0f * cc[h * D2_ + d] * x0[h * D2_ + d];
        #pragma unroll
        for (int k = 0; k < 6; ++k) {
            float len = (float)(32 << k);        // 32 * 2^k steps
            float e2  = __expf(av * T * len);
            float an  = tv * T * len;
            WPh[((size_t)h * 6 + k) * 64 + d]      = (_Float16)(e2 * __cosf(an));
            WPh[((size_t)h * 6 + k) * 64 + 32 + d] = (_Float16)(e2 * __sinf(an));
        }
    }
    __syncthreads();
    // phase 1: fk recurrence
    int q4 = t & 3, lc = t >> 2;
    float z0 = T * (float)(lc * 32);
    float pr[8], pi[8], wr[8], wi[8], qd[8], gx[8];
    #pragma unroll
    for (int j = 0; j < 8; ++j) {
        int d = q4 * 8 + j;
        float aa = avs[d], tv = tvs[d];
        float e0 = __expf(aa * z0);
        pr[j] = e0 * __cosf(tv * z0);
        pi[j] = e0 * __sinf(tv * z0);
        float e1 = __expf(aa * T);
        wr[j] = e1 * __cosf(tv * T);
        wi[j] = e1 * __sinf(tv * T);
        qd[j] = qds[d];
        gx[j] = gxs[d];
    }
    for (int i = 0; i < 32; ++i) {
        float fa = 0.f, ka = 0.f;
        #pragma unroll
        for (int j = 0; j < 8; ++j) {
            fa = fmaf(qd[j], pr[j], fa);
            ka = fmaf(gx[j], pr[j], ka);
            float nr = fmaf(pr[j], wr[j], -(pi[j] * wi[j]));
            float ni = fmaf(pr[j], wi[j],  (pi[j] * wr[j]));
            pr[j] = nr; pi[j] = ni;
        }
        fa += __shfl_xor(fa, 1); fa += __shfl_xor(fa, 2);
        ka += __shfl_xor(ka, 1); ka += __shfl_xor(ka, 2);
        if (q4 == 0) {
            float fv = 2.0f * T * fa;
            fk_all[i * 64 + lc] = pack_bf16x2(fv, ka);   // banks = lc&31: conflict-free
            if (lc == 0) f_lds[i] = fv;
        }
    }
    __syncthreads();
    // coalesced FKf store: thread t -> l = t*8..t*8+7
    {
        unsigned v[8];
        #pragma unroll
        for (int j = 0; j < 8; ++j) {
            int l = t * 8 + j;
            v[j] = fk_all[(l & 31) * 64 + (l >> 5)];
        }
        uint4* dst = (uint4*)(FKf + (size_t)h * L_ + t * 8);
        dst[0] = make_uint4(v[0], v[1], v[2], v[3]);
        dst[1] = make_uint4(v[4], v[5], v[6], v[7]);
    }
    // phase 2: operand matrices (fp16)
    for (int e = t; e < 64 * 32; e += 256) {
        int m = e >> 5, i = e & 31;
        int d = m & 31;
        float av = avs[d], tv = tvs[d];
        float z  = T * (float)(31 - i);
        float ex = __expf(av * z);
        float v  = (m < 32) ? ex * __cosf(tv * z) : ex * __sinf(tv * z);
        AB[(size_t)h * 2048 + e] = (_Float16)v;
    }
    for (int e = t; e < 32 * 96; e += 256) {
        int i = e / 96, k = e - i * 96;
        float v = 0.f;
        if (k < 32) {
            if (k <= i) v = f_lds[i - k];
        } else {
            int d = (k < 64) ? k - 32 : k - 64;
            float av = avs[d], tv = tvs[d];
            float qs = 2.0f * T * qds[d];
            float z  = T * (float)(i + 1);
            float ex = __expf(av * z);
            v = (k < 64) ? qs * ex * __cosf(tv * z) : -qs * ex * __sinf(tv * z);
        }
        CB[(size_t)h * 3072 + e] = (_Float16)v;
    }
}

// ---------------- scan_mfma (R4-proven, untouched): 2 waves per (b,h) ----------------
// Grid (h, b): flat id = h + 512*b -> XCD = h%8, so all 8 b-blocks of an h share
// one XCD's L2 for AB/CB/FKf/WPh — already optimal.
__global__ __launch_bounds__(128, 6) void scan_mfma_kernel(
        const float* __restrict__ u, const _Float16* __restrict__ AB,
        const _Float16* __restrict__ CB, const unsigned* __restrict__ WPh,
        const float* __restrict__ Dp, const unsigned* __restrict__ FKf,
        __hip_bfloat16* __restrict__ y) {
    __shared__ __align__(16) unsigned El[64 * EP];
    int wid = threadIdx.x >> 6, lane = threadIdx.x & 63;
    int h = blockIdx.x, b = blockIdx.y;
    int ln = lane & 15, qq = lane >> 4;
    const float* ug = u + (size_t)(b * H_ + h) * L_;

    // ---- U fragments (fp16), all 4 column-tiles (needed as M1 B-operand) ----
    half8 uf[4];
    #pragma unroll
    for (int nb = 0; nb < 4; ++nb) {
        const float* p = ug + (nb * 16 + ln) * 32 + qq * 8;
        float4 a0 = *(const float4*)p;
        float4 a1 = *(const float4*)(p + 4);
        unsigned* vp = (unsigned*)&uf[nb];
        vp[0] = pack_f16x2(a0.x, a0.y);
        vp[1] = pack_f16x2(a0.z, a0.w);
        vp[2] = pack_f16x2(a1.x, a1.y);
        vp[3] = pack_f16x2(a1.z, a1.w);
    }

    // ---- M1: this wave's Er/Ei rows (d-half) ----
    const _Float16* ABh = AB + (size_t)h * 2048;
    int j0 = wid * 8 + qq * 2;
    #pragma unroll
    for (int e = 0; e < 2; ++e) {       // e=0: Re rows, e=1: Im rows
        half8 af = *(const half8*)&ABh[(e * 32 + wid * 16 + ln) * 32 + qq * 8];
        #pragma unroll
        for (int nb = 0; nb < 4; ++nb) {
            float4v acc = (float4v){0.f, 0.f, 0.f, 0.f};
            acc = __builtin_amdgcn_mfma_f32_16x16x32_f16(af, uf[nb], acc, 0, 0, 0);
            unsigned p0 = pack_f16x2(acc[0], acc[1]);
            unsigned p1 = pack_f16x2(acc[2], acc[3]);
            *(uint2*)&El[(nb * 16 + ln) * EP + e * 16 + j0] = make_uint2(p0, p1);
        }
    }
    // own-wave write->read: DS ops drain, no cross-wave dependency yet
    asm volatile("s_waitcnt lgkmcnt(0)" ::: "memory");
    __builtin_amdgcn_sched_barrier(0);

    // ---- packed-fp16 scan over chunks (lane = c), own 8 pairs ----
    int c = lane;
    unsigned sr[8], si[8];
    {
        const unsigned* rp = &El[c * EP + wid * 8];
        uint4 r0 = *(const uint4*)rp;
        uint4 r1 = *(const uint4*)(rp + 4);
        uint4 i0 = *(const uint4*)(rp + 16);
        uint4 i1 = *(const uint4*)(rp + 20);
        sr[0]=r0.x; sr[1]=r0.y; sr[2]=r0.z; sr[3]=r0.w;
        sr[4]=r1.x; sr[5]=r1.y; sr[6]=r1.z; sr[7]=r1.w;
        si[0]=i0.x; si[1]=i0.y; si[2]=i0.z; si[3]=i0.w;
        si[4]=i1.x; si[5]=i1.y; si[6]=i1.z; si[7]=i1.w;
    }
    const unsigned* mpb = WPh + (size_t)h * 6 * 32;
    #pragma unroll
    for (int st = 0; st < 6; ++st) {
        int off = 1 << st;
        int src = (c - off) & 63;
        bool act = c >= off;
        const unsigned* mp = mpb + st * 32 + wid * 8;
        #pragma unroll
        for (int jj = 0; jj < 8; ++jj) {
            unsigned prp = (unsigned)__shfl((int)sr[jj], src);
            unsigned pip = (unsigned)__shfl((int)si[jj], src);
            if (!act) { prp = 0u; pip = 0u; }
            unsigned mru = mp[jj];
            unsigned miu = mp[16 + jj];
            unsigned min_ = miu ^ 0x80008000u;          // -Mi via sign flip
            half2v pr = *(half2v*)&prp, pi = *(half2v*)&pip;
            half2v Mr = *(half2v*)&mru, Mi = *(half2v*)&miu, Mni = *(half2v*)&min_;
            half2v s_r = *(half2v*)&sr[jj], s_i = *(half2v*)&si[jj];
            half2v nr = pk_fma16(pr, Mr, pk_fma16(pi, Mni, s_r));
            half2v ni = pk_fma16(pr, Mi, pk_fma16(pi, Mr,  s_i));
            sr[jj] = *(unsigned*)&nr; si[jj] = *(unsigned*)&ni;
        }
    }
    {   // exclusive shift: carry entering chunk c = S_{c-1}; lane 0 -> 0
        int srcm1 = (c - 1) & 63;
        #pragma unroll
        for (int jj = 0; jj < 8; ++jj) {
            unsigned a0 = (unsigned)__shfl((int)sr[jj], srcm1);
            unsigned b0 = (unsigned)__shfl((int)si[jj], srcm1);
            if (c == 0) { a0 = 0u; b0 = 0u; }
            sr[jj] = a0; si[jj] = b0;
        }
    }
    {   // carries back to same El slots
        unsigned* wp = &El[c * EP + wid * 8];
        *(uint4*)wp        = make_uint4(sr[0], sr[1], sr[2], sr[3]);
        *(uint4*)(wp + 4)  = make_uint4(sr[4], sr[5], sr[6], sr[7]);
        *(uint4*)(wp + 16) = make_uint4(si[0], si[1], si[2], si[3]);
        *(uint4*)(wp + 20) = make_uint4(si[4], si[5], si[6], si[7]);
    }
    // prefetch FK for epilogue; latency hides under barrier + M2
    const unsigned* fgh = FKf + (size_t)h * L_;
    uint4 fkp[2][2];
    #pragma unroll
    for (int nbi = 0; nbi < 2; ++nbi) {
        int col = (2 * wid + nbi) * 16 + ln;
        fkp[nbi][0] = *(const uint4*)&fgh[col * 32 + qq * 4];
        fkp[nbi][1] = *(const uint4*)&fgh[col * 32 + 16 + qq * 4];
    }
    __syncthreads();

    // ---- M2: y_pre = [T_f | Qr | -Qi] @ [U; Sr; Si], this wave's 2 col-tiles ----
    const _Float16* CBh = CB + (size_t)h * 3072;
    float4v acc2[2][2];
    #pragma unroll
    for (int mb = 0; mb < 2; ++mb)
        #pragma unroll
        for (int nbi = 0; nbi < 2; ++nbi)
            acc2[mb][nbi] = (float4v){0.f, 0.f, 0.f, 0.f};
    #pragma unroll
    for (int ks = 0; ks < 3; ++ks) {
        half8 a2[2];
        a2[0] = *(const half8*)&CBh[(ln)      * 96 + ks * 32 + qq * 8];
        a2[1] = *(const half8*)&CBh[(16 + ln) * 96 + ks * 32 + qq * 8];
        #pragma unroll
        for (int nbi = 0; nbi < 2; ++nbi) {
            int col = (2 * wid + nbi) * 16 + ln;
            half8 bfv;
            if (ks == 0) bfv = uf[2 * wid + nbi];
            else {
                int off = (ks == 1) ? 0 : 16;
                bfv = *(const half8*)&El[col * EP + off + qq * 4];
            }
            acc2[0][nbi] = __builtin_amdgcn_mfma_f32_16x16x32_f16(a2[0], bfv, acc2[0][nbi], 0, 0, 0);
            acc2[1][nbi] = __builtin_amdgcn_mfma_f32_16x16x32_f16(a2[1], bfv, acc2[1][nbi], 0, 0, 0);
        }
    }

    // ---- epilogue: y = y_pre + c0*u + c1*f + k0, fast gelu, pack bf16 ----
    float f0; { f0 = unpack_bf16x2(fgh[0]).x; }
    float c0v = Dp[h] - 0.5f * f0;
    float c1v = -0.5f * ug[0];
    #pragma unroll
    for (int nbi = 0; nbi < 2; ++nbi) {
        int col = (2 * wid + nbi) * 16 + ln;
        #pragma unroll
        for (int mb = 0; mb < 2; ++mb) {
            int l0 = col * 32 + mb * 16 + qq * 4;
            float4 u4 = *(const float4*)(ug + l0);
            uint4 fkv = fkp[nbi][mb];
            float us[4] = {u4.x, u4.y, u4.z, u4.w};
            unsigned fs[4] = {fkv.x, fkv.y, fkv.z, fkv.w};
            float g[4];
            #pragma unroll
            for (int r = 0; r < 4; ++r) {
                float2 fk = unpack_bf16x2(fs[r]);
                float yv = acc2[mb][nbi][r] + fmaf(c0v, us[r], fmaf(c1v, fk.x, fk.y));
                g[r] = gelu_fast(yv);
            }
            uint2 yo;
            yo.x = pack_bf16x2(g[0], g[1]);
            yo.y = pack_bf16x2(g[2], g[3]);
            *(uint2*)((short*)y + (size_t)(b * H_ + h) * L_ + l0) = yo;
        }
    }
}

// ---------------- gemm v4: depth-2 B prefetch ----------------
// R8/R9's depth-1 pipeline consumed za/zb loaded at the TOP OF THE SAME STEP:
// the implicit vmcnt wait before the Bs write exposed ~300cy of load latency
// per K-step, in barrier-lockstep across the block's waves. Depth-2: issue
// kt+2's loads this step, write Bs[nxt] from regs loaded a FULL STEP ago
// (landed; vmcnt wait ~0). The barrier's vmcnt(0) drain covers loads that
// have had a whole step in flight. Math/layouts byte-identical (verified).
__global__ __launch_bounds__(256) void gemm_kernel(
        const __hip_bfloat16* __restrict__ Wb, const __hip_bfloat16* __restrict__ y,
        const float* __restrict__ bias, float* __restrict__ out) {
    __shared__ __align__(16) short    As[2][64 * 32];
    __shared__ __align__(16) unsigned Bs[2][128 * 16];
    int l0 = blockIdx.x * 128;
    int h0 = blockIdx.y * 64;
    int b  = blockIdx.z;
    int t    = threadIdx.x;
    int lane = t & 63, wave = t >> 6;
    int m_off = (wave >> 1) * 32, n_off = (wave & 1) * 64;
    int quad = lane >> 4, ln = lane & 15;

    float4v acc[2][4];
    #pragma unroll
    for (int mt = 0; mt < 2; ++mt)
        #pragma unroll
        for (int nt = 0; nt < 4; ++nt)
            acc[mt][nt] = (float4v){0.f, 0.f, 0.f, 0.f};

    const short* Wg = (const short*)Wb;
    const short* Yg = (const short*)y + (size_t)b * 512 * L_;   // [f][l]

    int r  = t >> 2;       // 0..63 (A staging)
    int qd = t & 3;
    int fp = t & 15;       // B staging: f-pair 0..15
    int n8 = t >> 4;       // B staging: l-octet 0..15
    const short* ybase = Yg + (size_t)(2 * fp) * L_ + l0 + n8 * 8;

    // prologue: issue A(0), B(0), B(1) loads; write Bs[0]; barrier.
    load_lds16(Wg + (h0 + r) * 512 + qd * 8, &As[0][t * 8]);
    uint4 ya0 = *(const uint4*)ybase;
    uint4 yb0 = *(const uint4*)(ybase + L_);
    uint4 za1 = *(const uint4*)(ybase + (size_t)32 * L_);      // kt=1
    uint4 zb1 = *(const uint4*)(ybase + (size_t)33 * L_);
    {
        unsigned au[4] = {ya0.x, ya0.y, ya0.z, ya0.w};
        unsigned bu[4] = {yb0.x, yb0.y, yb0.z, yb0.w};
        #pragma unroll
        for (int i2 = 0; i2 < 4; ++i2) {
            int na = n8 * 8 + 2 * i2, nb = na + 1;
            Bs[0][na * 16 + (fp ^ (((na >> 2) & 3) << 2))] = (au[i2] & 0xFFFFu) | (bu[i2] << 16);
            Bs[0][nb * 16 + (fp ^ (((nb >> 2) & 3) << 2))] = (au[i2] >> 16) | (bu[i2] & 0xFFFF0000u);
        }
    }
    __syncthreads();

    for (int kt = 0; kt < 15; ++kt) {
        int cur = kt & 1, nxt = cur ^ 1;
        int k1 = (kt + 1) * 32;
        // issue A(kt+1) and B(kt+2); both consumed a full step later
        load_lds16(Wg + (h0 + r) * 512 + k1 + qd * 8, &As[nxt][t * 8]);
        uint4 za2, zb2;
        if (kt < 14) {
            int k2 = (kt + 2) * 32;
            za2 = *(const uint4*)(ybase + (size_t)k2 * L_);
            zb2 = *(const uint4*)(ybase + (size_t)(k2 + 1) * L_);
        }

        short8 af[2], bf[4];
        #pragma unroll
        for (int mt = 0; mt < 2; ++mt)
            af[mt] = *(const short8*)&As[cur][(m_off + mt * 16 + ln) * 32 + quad * 8];
        #pragma unroll
        for (int nt = 0; nt < 4; ++nt) {
            int n = n_off + nt * 16 + ln;
            bf[nt] = *(const short8*)&Bs[cur][n * 16 + ((quad * 4) ^ (((n >> 2) & 3) << 2))];
        }
        #pragma unroll
        for (int mt = 0; mt < 2; ++mt)
            #pragma unroll
            for (int nt = 0; nt < 4; ++nt)
                acc[mt][nt] = __builtin_amdgcn_mfma_f32_16x16x32_bf16(
                    af[mt], bf[nt], acc[mt][nt], 0, 0, 0);
        __builtin_amdgcn_sched_barrier(0);   // keep B-write below the MFMA cluster

        {   // write Bs[kt+1] from regs loaded LAST step (vmcnt wait ~0)
            unsigned au[4] = {za1.x, za1.y, za1.z, za1.w};
            unsigned bu[4] = {zb1.x, zb1.y, zb1.z, zb1.w};
            #pragma unroll
            for (int i2 = 0; i2 < 4; ++i2) {
                int na = n8 * 8 + 2 * i2, nb = na + 1;
                Bs[nxt][na * 16 + (fp ^ (((na >> 2) & 3) << 2))] = (au[i2] & 0xFFFFu) | (bu[i2] << 16);
                Bs[nxt][nb * 16 + (fp ^ (((nb >> 2) & 3) << 2))] = (au[i2] >> 16) | (bu[i2] & 0xFFFF0000u);
            }
        }
        za1 = za2; zb1 = zb2;               // rotate pipeline regs
        __syncthreads();
    }
    {   // tail: kt = 15, buffer 1, compute only
        short8 af[2], bf[4];
        #pragma unroll
        for (int mt = 0; mt < 2; ++mt)
            af[mt] = *(const short8*)&As[1][(m_off + mt * 16 + ln) * 32 + quad * 8];
        #pragma unroll
        for (int nt = 0; nt < 4; ++nt) {
            int n = n_off + nt * 16 + ln;
            bf[nt] = *(const short8*)&Bs[1][n * 16 + ((quad * 4) ^ (((n >> 2) & 3) << 2))];
        }
        #pragma unroll
        for (int mt = 0; mt < 2; ++mt)
            #pragma unroll
            for (int nt = 0; nt < 4; ++nt)
                acc[mt][nt] = __builtin_amdgcn_mfma_f32_16x16x32_bf16(
                    af[mt], bf[nt], acc[mt][nt], 0, 0, 0);
    }

    #pragma unroll
    for (int mt = 0; mt < 2; ++mt) {
        #pragma unroll
        for (int nt = 0; nt < 4; ++nt) {
            int hh = h0 + m_off + mt * 16 + quad * 4;
            int ll = l0 + n_off + nt * 16 + ln;
            #pragma unroll
            for (int r2 = 0; r2 < 4; ++r2)
                out[((size_t)(b * H_ + hh + r2)) * L_ + ll] = acc[mt][nt][r2] + bias[hh + r2];
        }
    }
}

extern "C" void kernel_launch(void* const* d_in, const int* in_sizes, int n_in,
                              void* d_out, int out_size, void* d_ws, size_t ws_size,
                              hipStream_t stream) {
    const float* u    = (const float*)d_in[0];
    const float* a    = (const float*)d_in[1];
    const float* th   = (const float*)d_in[2];
    const float* bb   = (const float*)d_in[3];
    const float* cc   = (const float*)d_in[4];
    const float* x0   = (const float*)d_in[5];
    const float* Dp   = (const float*)d_in[6];
    const float* W    = (const float*)d_in[7];
    const float* bias = (const float*)d_in[8];
    float* out = (float*)d_out;
    char* ws = (char*)d_ws;

    // layout: FKf 4M @0 | y 16M @20M | Wb 0.5M @36M | AB 2M @37M |
    //         CB 3M @39M | WPh fp16 384KB @42M
    unsigned*       FKf = (unsigned*)ws;
    __hip_bfloat16* y   = (__hip_bfloat16*)(ws + (20ull << 20));
    __hip_bfloat16* Wb  = (__hip_bfloat16*)(ws + (36ull << 20));
    _Float16*       AB  = (_Float16*)(ws + (37ull << 20));
    _Float16*       CB  = (_Float16*)(ws + (39ull << 20));
    _Float16*       WPh = (_Float16*)(ws + (42ull << 20));

    hipLaunchKernelGGL(fkprep_kernel,     dim3(H_),        dim3(256), 0, stream,
                       a, th, bb, cc, x0, W, Wb, FKf, AB, CB, WPh);
    hipLaunchKernelGGL(scan_mfma_kernel,  dim3(H_, B_),    dim3(128), 0, stream,
                       u, AB, CB, (const unsigned*)WPh, Dp, FKf, y);
    hipLaunchKernelGGL(gemm_kernel,       dim3(16, 8, 8),  dim3(256), 0, stream,
                       Wb, y, bias, out);
}

// Round 11
// 162.112 us; speedup vs baseline: 1.0096x; 1.0096x over previous
//
#include <hip/hip_runtime.h>
#include <hip/hip_bf16.h>

#define B_  8
#define H_  512
#define L_  2048
#define D2_ 32
#define NC_ 64
#define LC_ 32    // L_/NC_
#define EP  36    // E_lds row pitch in u32 (16B-aligned rows)

typedef __attribute__((ext_vector_type(8))) short short8;     // 8 bf16 (4 VGPRs)
typedef __attribute__((ext_vector_type(8))) _Float16 half8;   // 8 fp16 (4 VGPRs)
typedef __attribute__((ext_vector_type(2))) _Float16 half2v;  // packed fp16 (v_pk_*)
typedef __attribute__((ext_vector_type(4))) float float4v;    // 4 fp32 acc

__device__ __forceinline__ half2v pk_fma16(half2v a, half2v b, half2v c) {
    return __builtin_elementwise_fma(a, b, c);
}

// tanh-form GELU: max |err| vs exact ~3e-4, far below bf16 y-storage ulp.
__device__ __forceinline__ float gelu_fast(float x) {
    float q = x * fmaf(0.044715f, x * x, 1.0f);
    float s = __expf(-1.5957691216057308f * q);   // e^{-2*0.79788456*q}
    return __fdividef(x, 1.0f + s);               // x * sigmoid(2w)
}

__device__ __forceinline__ unsigned pack_bf16x2(float x, float y) {
    __hip_bfloat162 p = __float22bfloat162_rn(make_float2(x, y));
    return *(unsigned*)&p;
}
__device__ __forceinline__ float2 unpack_bf16x2(unsigned v) {
    __hip_bfloat162 p = *(__hip_bfloat162*)&v;
    return __bfloat1622float2(p);
}
__device__ __forceinline__ unsigned pack_f16x2(float x, float y) {
    auto v = __builtin_amdgcn_cvt_pkrtz(x, y);    // v_cvt_pkrtz_f16_f32
    return *(unsigned*)&v;
}

__device__ __forceinline__ void load_lds16(const void* g, void* l) {
    __builtin_amdgcn_global_load_lds((const __attribute__((address_space(1))) unsigned int*)g,
                                     (__attribute__((address_space(3))) unsigned int*)l, 16, 0, 0);
}

// ---------------- fkprep: params + fk (f,k0) + MFMA operands + W-cast, 1 block/h ----
__global__ __launch_bounds__(256) void fkprep_kernel(
        const float* __restrict__ a, const float* __restrict__ th,
        const float* __restrict__ bb, const float* __restrict__ cc,
        const float* __restrict__ x0, const float* __restrict__ W,
        __hip_bfloat16* __restrict__ Wb, unsigned* __restrict__ FKf,
        _Float16* __restrict__ AB, _Float16* __restrict__ CB,
        _Float16* __restrict__ WPh) {
    __shared__ float avs[32], tvs[32], qds[32], gxs[32], f_lds[32];
    __shared__ unsigned fk_all[32 * 64];     // [i][lc]
    int h = blockIdx.x;
    int t = threadIdx.x;
    const float T = 1.0f / (float)(L_ - 1);
    // W row cast (independent of everything else)
    Wb[(size_t)h * 512 + t]       = __float2bfloat16(W[(size_t)h * 512 + t]);
    Wb[(size_t)h * 512 + t + 256] = __float2bfloat16(W[(size_t)h * 512 + t + 256]);
    // phase 0: per-d params + WPh
    if (t < 32) {
        int d = t;
        float av = -fabsf(a[h * D2_ + d]);
        float tv = th[h * D2_ + d];
        avs[d] = av; tvs[d] = tv;
        qds[d] = bb[h * D2_ + d] * cc[h * D2_ + d];
        gxs[d] = 2.0f * cc[h * D2_ + d] * x0[h * D2_ + d];
        #pragma unroll
        for (int k = 0; k < 6; ++k) {
            float len = (float)(32 << k);        // 32 * 2^k steps
            float e2  = __expf(av * T * len);
            float an  = tv * T * len;
            WPh[((size_t)h * 6 + k) * 64 + d]      = (_Float16)(e2 * __cosf(an));
            WPh[((size_t)h * 6 + k) * 64 + 32 + d] = (_Float16)(e2 * __sinf(an));
        }
    }
    __syncthreads();
    // phase 1: fk recurrence
    int q4 = t & 3, lc = t >> 2;
    float z0 = T * (float)(lc * 32);
    float pr[8], pi[8], wr[8], wi[8], qd[8], gx[8];
    #pragma unroll
    for (int j = 0; j < 8; ++j) {
        int d = q4 * 8 + j;
        float aa = avs[d], tv = tvs[d];
        float e0 = __expf(aa * z0);
        pr[j] = e0 * __cosf(tv * z0);
        pi[j] = e0 * __sinf(tv * z0);
        float e1 = __expf(aa * T);
        wr[j] = e1 * __cosf(tv * T);
        wi[j] = e1 * __sinf(tv * T);
        qd[j] = qds[d];
        gx[j] = gxs[d];
    }
    for (int i = 0; i < 32; ++i) {
        float fa = 0.f, ka = 0.f;
        #pragma unroll
        for (int j = 0; j < 8; ++j) {
            fa = fmaf(qd[j], pr[j], fa);
            ka = fmaf(gx[j], pr[j], ka);
            float nr = fmaf(pr[j], wr[j], -(pi[j] * wi[j]));
            float ni = fmaf(pr[j], wi[j],  (pi[j] * wr[j]));
            pr[j] = nr; pi[j] = ni;
        }
        fa += __shfl_xor(fa, 1); fa += __shfl_xor(fa, 2);
        ka += __shfl_xor(ka, 1); ka += __shfl_xor(ka, 2);
        if (q4 == 0) {
            float fv = 2.0f * T * fa;
            fk_all[i * 64 + lc] = pack_bf16x2(fv, ka);   // banks = lc&31: conflict-free
            if (lc == 0) f_lds[i] = fv;
        }
    }
    __syncthreads();
    // coalesced FKf store: thread t -> l = t*8..t*8+7
    {
        unsigned v[8];
        #pragma unroll
        for (int j = 0; j < 8; ++j) {
            int l = t * 8 + j;
            v[j] = fk_all[(l & 31) * 64 + (l >> 5)];
        }
        uint4* dst = (uint4*)(FKf + (size_t)h * L_ + t * 8);
        dst[0] = make_uint4(v[0], v[1], v[2], v[3]);
        dst[1] = make_uint4(v[4], v[5], v[6], v[7]);
    }
    // phase 2: operand matrices (fp16)
    for (int e = t; e < 64 * 32; e += 256) {
        int m = e >> 5, i = e & 31;
        int d = m & 31;
        float av = avs[d], tv = tvs[d];
        float z  = T * (float)(31 - i);
        float ex = __expf(av * z);
        float v  = (m < 32) ? ex * __cosf(tv * z) : ex * __sinf(tv * z);
        AB[(size_t)h * 2048 + e] = (_Float16)v;
    }
    for (int e = t; e < 32 * 96; e += 256) {
        int i = e / 96, k = e - i * 96;
        float v = 0.f;
        if (k < 32) {
            if (k <= i) v = f_lds[i - k];
        } else {
            int d = (k < 64) ? k - 32 : k - 64;
            float av = avs[d], tv = tvs[d];
            float qs = 2.0f * T * qds[d];
            float z  = T * (float)(i + 1);
            float ex = __expf(av * z);
            v = (k < 64) ? qs * ex * __cosf(tv * z) : -qs * ex * __sinf(tv * z);
        }
        CB[(size_t)h * 3072 + e] = (_Float16)v;
    }
}

// ---------------- scan_mfma v5: 2 sub-problems (b) per 256-thread block ----------------
// R4's 2-wave blocks at grid 4096 sat at ~44% occupancy (~14 waves/CU) despite
// VGPR=40 / LDS=9.2KB / wave-slots all permitting 32 waves/CU — consistent with a
// per-CU block-slot cap (~8-10 blocks). Merging two (b,h) sub-problems per block
// (sub = tid>>7 -> b = 2*by+sub) halves block count: 2048 blocks, 8/CU x 4 waves
// = 32 waves/CU in the same LDS/VGPR budget. Per-thread code is the R4-verified
// path verbatim on El[sub]; the one barrier now syncs 4 waves (M1->scan stays
// own-wave lgkmcnt). Both subs share h -> AB/CB/FKf reads hit L1 across waves.
__global__ __launch_bounds__(256, 6) void scan_mfma_kernel(
        const float* __restrict__ u, const _Float16* __restrict__ AB,
        const _Float16* __restrict__ CB, const unsigned* __restrict__ WPh,
        const float* __restrict__ Dp, const unsigned* __restrict__ FKf,
        __hip_bfloat16* __restrict__ y) {
    __shared__ __align__(16) unsigned El2[2][64 * EP];
    int tid = threadIdx.x;
    int sub = tid >> 7;                 // which (b) sub-problem
    int wid = (tid >> 6) & 1, lane = tid & 63;
    int h = blockIdx.x, b = blockIdx.y * 2 + sub;
    int ln = lane & 15, qq = lane >> 4;
    unsigned* El = El2[sub];
    const float* ug = u + (size_t)(b * H_ + h) * L_;

    // ---- U fragments (fp16), all 4 column-tiles (needed as M1 B-operand) ----
    half8 uf[4];
    #pragma unroll
    for (int nb = 0; nb < 4; ++nb) {
        const float* p = ug + (nb * 16 + ln) * 32 + qq * 8;
        float4 a0 = *(const float4*)p;
        float4 a1 = *(const float4*)(p + 4);
        unsigned* vp = (unsigned*)&uf[nb];
        vp[0] = pack_f16x2(a0.x, a0.y);
        vp[1] = pack_f16x2(a0.z, a0.w);
        vp[2] = pack_f16x2(a1.x, a1.y);
        vp[3] = pack_f16x2(a1.z, a1.w);
    }

    // ---- M1: this wave's Er/Ei rows (d-half) ----
    const _Float16* ABh = AB + (size_t)h * 2048;
    int j0 = wid * 8 + qq * 2;
    #pragma unroll
    for (int e = 0; e < 2; ++e) {       // e=0: Re rows, e=1: Im rows
        half8 af = *(const half8*)&ABh[(e * 32 + wid * 16 + ln) * 32 + qq * 8];
        #pragma unroll
        for (int nb = 0; nb < 4; ++nb) {
            float4v acc = (float4v){0.f, 0.f, 0.f, 0.f};
            acc = __builtin_amdgcn_mfma_f32_16x16x32_f16(af, uf[nb], acc, 0, 0, 0);
            unsigned p0 = pack_f16x2(acc[0], acc[1]);
            unsigned p1 = pack_f16x2(acc[2], acc[3]);
            *(uint2*)&El[(nb * 16 + ln) * EP + e * 16 + j0] = make_uint2(p0, p1);
        }
    }
    // own-wave write->read: DS ops drain, no cross-wave dependency yet
    asm volatile("s_waitcnt lgkmcnt(0)" ::: "memory");
    __builtin_amdgcn_sched_barrier(0);

    // ---- packed-fp16 scan over chunks (lane = c), own 8 pairs ----
    int c = lane;
    unsigned sr[8], si[8];
    {
        const unsigned* rp = &El[c * EP + wid * 8];
        uint4 r0 = *(const uint4*)rp;
        uint4 r1 = *(const uint4*)(rp + 4);
        uint4 i0 = *(const uint4*)(rp + 16);
        uint4 i1 = *(const uint4*)(rp + 20);
        sr[0]=r0.x; sr[1]=r0.y; sr[2]=r0.z; sr[3]=r0.w;
        sr[4]=r1.x; sr[5]=r1.y; sr[6]=r1.z; sr[7]=r1.w;
        si[0]=i0.x; si[1]=i0.y; si[2]=i0.z; si[3]=i0.w;
        si[4]=i1.x; si[5]=i1.y; si[6]=i1.z; si[7]=i1.w;
    }
    const unsigned* mpb = WPh + (size_t)h * 6 * 32;
    #pragma unroll
    for (int st = 0; st < 6; ++st) {
        int off = 1 << st;
        int src = (c - off) & 63;
        bool act = c >= off;
        const unsigned* mp = mpb + st * 32 + wid * 8;
        #pragma unroll
        for (int jj = 0; jj < 8; ++jj) {
            unsigned prp = (unsigned)__shfl((int)sr[jj], src);
            unsigned pip = (unsigned)__shfl((int)si[jj], src);
            if (!act) { prp = 0u; pip = 0u; }
            unsigned mru = mp[jj];
            unsigned miu = mp[16 + jj];
            unsigned min_ = miu ^ 0x80008000u;          // -Mi via sign flip
            half2v pr = *(half2v*)&prp, pi = *(half2v*)&pip;
            half2v Mr = *(half2v*)&mru, Mi = *(half2v*)&miu, Mni = *(half2v*)&min_;
            half2v s_r = *(half2v*)&sr[jj], s_i = *(half2v*)&si[jj];
            half2v nr = pk_fma16(pr, Mr, pk_fma16(pi, Mni, s_r));
            half2v ni = pk_fma16(pr, Mi, pk_fma16(pi, Mr,  s_i));
            sr[jj] = *(unsigned*)&nr; si[jj] = *(unsigned*)&ni;
        }
    }
    {   // exclusive shift: carry entering chunk c = S_{c-1}; lane 0 -> 0
        int srcm1 = (c - 1) & 63;
        #pragma unroll
        for (int jj = 0; jj < 8; ++jj) {
            unsigned a0 = (unsigned)__shfl((int)sr[jj], srcm1);
            unsigned b0 = (unsigned)__shfl((int)si[jj], srcm1);
            if (c == 0) { a0 = 0u; b0 = 0u; }
            sr[jj] = a0; si[jj] = b0;
        }
    }
    {   // carries back to same El slots
        unsigned* wp = &El[c * EP + wid * 8];
        *(uint4*)wp        = make_uint4(sr[0], sr[1], sr[2], sr[3]);
        *(uint4*)(wp + 4)  = make_uint4(sr[4], sr[5], sr[6], sr[7]);
        *(uint4*)(wp + 16) = make_uint4(si[0], si[1], si[2], si[3]);
        *(uint4*)(wp + 20) = make_uint4(si[4], si[5], si[6], si[7]);
    }
    // prefetch FK for epilogue; latency hides under barrier + M2
    const unsigned* fgh = FKf + (size_t)h * L_;
    uint4 fkp[2][2];
    #pragma unroll
    for (int nbi = 0; nbi < 2; ++nbi) {
        int col = (2 * wid + nbi) * 16 + ln;
        fkp[nbi][0] = *(const uint4*)&fgh[col * 32 + qq * 4];
        fkp[nbi][1] = *(const uint4*)&fgh[col * 32 + 16 + qq * 4];
    }
    __syncthreads();

    // ---- M2: y_pre = [T_f | Qr | -Qi] @ [U; Sr; Si], this wave's 2 col-tiles ----
    const _Float16* CBh = CB + (size_t)h * 3072;
    float4v acc2[2][2];
    #pragma unroll
    for (int mb = 0; mb < 2; ++mb)
        #pragma unroll
        for (int nbi = 0; nbi < 2; ++nbi)
            acc2[mb][nbi] = (float4v){0.f, 0.f, 0.f, 0.f};
    #pragma unroll
    for (int ks = 0; ks < 3; ++ks) {
        half8 a2[2];
        a2[0] = *(const half8*)&CBh[(ln)      * 96 + ks * 32 + qq * 8];
        a2[1] = *(const half8*)&CBh[(16 + ln) * 96 + ks * 32 + qq * 8];
        #pragma unroll
        for (int nbi = 0; nbi < 2; ++nbi) {
            int col = (2 * wid + nbi) * 16 + ln;
            half8 bfv;
            if (ks == 0) bfv = uf[2 * wid + nbi];
            else {
                int off = (ks == 1) ? 0 : 16;
                bfv = *(const half8*)&El[col * EP + off + qq * 4];
            }
            acc2[0][nbi] = __builtin_amdgcn_mfma_f32_16x16x32_f16(a2[0], bfv, acc2[0][nbi], 0, 0, 0);
            acc2[1][nbi] = __builtin_amdgcn_mfma_f32_16x16x32_f16(a2[1], bfv, acc2[1][nbi], 0, 0, 0);
        }
    }

    // ---- epilogue: y = y_pre + c0*u + c1*f + k0, fast gelu, pack bf16 ----
    float f0; { f0 = unpack_bf16x2(fgh[0]).x; }
    float c0v = Dp[h] - 0.5f * f0;
    float c1v = -0.5f * ug[0];
    #pragma unroll
    for (int nbi = 0; nbi < 2; ++nbi) {
        int col = (2 * wid + nbi) * 16 + ln;
        #pragma unroll
        for (int mb = 0; mb < 2; ++mb) {
            int l0 = col * 32 + mb * 16 + qq * 4;
            float4 u4 = *(const float4*)(ug + l0);
            uint4 fkv = fkp[nbi][mb];
            float us[4] = {u4.x, u4.y, u4.z, u4.w};
            unsigned fs[4] = {fkv.x, fkv.y, fkv.z, fkv.w};
            float g[4];
            #pragma unroll
            for (int r = 0; r < 4; ++r) {
                float2 fk = unpack_bf16x2(fs[r]);
                float yv = acc2[mb][nbi][r] + fmaf(c0v, us[r], fmaf(c1v, fk.x, fk.y));
                g[r] = gelu_fast(yv);
            }
            uint2 yo;
            yo.x = pack_bf16x2(g[0], g[1]);
            yo.y = pack_bf16x2(g[2], g[3]);
            *(uint2*)((short*)y + (size_t)(b * H_ + h) * L_ + l0) = yo;
        }
    }
}

// ---------------- gemm v4 (R10): depth-2 B prefetch, XCD-correct grid ----------------
__global__ __launch_bounds__(256) void gemm_kernel(
        const __hip_bfloat16* __restrict__ Wb, const __hip_bfloat16* __restrict__ y,
        const float* __restrict__ bias, float* __restrict__ out) {
    __shared__ __align__(16) short    As[2][64 * 32];
    __shared__ __align__(16) unsigned Bs[2][128 * 16];
    int l0 = blockIdx.x * 128;
    int h0 = blockIdx.y * 64;
    int b  = blockIdx.z;
    int t    = threadIdx.x;
    int lane = t & 63, wave = t >> 6;
    int m_off = (wave >> 1) * 32, n_off = (wave & 1) * 64;
    int quad = lane >> 4, ln = lane & 15;

    float4v acc[2][4];
    #pragma unroll
    for (int mt = 0; mt < 2; ++mt)
        #pragma unroll
        for (int nt = 0; nt < 4; ++nt)
            acc[mt][nt] = (float4v){0.f, 0.f, 0.f, 0.f};

    const short* Wg = (const short*)Wb;
    const short* Yg = (const short*)y + (size_t)b * 512 * L_;   // [f][l]

    int r  = t >> 2;       // 0..63 (A staging)
    int qd = t & 3;
    int fp = t & 15;       // B staging: f-pair 0..15
    int n8 = t >> 4;       // B staging: l-octet 0..15
    const short* ybase = Yg + (size_t)(2 * fp) * L_ + l0 + n8 * 8;

    // prologue: issue A(0), B(0), B(1) loads; write Bs[0]; barrier.
    load_lds16(Wg + (h0 + r) * 512 + qd * 8, &As[0][t * 8]);
    uint4 ya0 = *(const uint4*)ybase;
    uint4 yb0 = *(const uint4*)(ybase + L_);
    uint4 za1 = *(const uint4*)(ybase + (size_t)32 * L_);      // kt=1
    uint4 zb1 = *(const uint4*)(ybase + (size_t)33 * L_);
    {
        unsigned au[4] = {ya0.x, ya0.y, ya0.z, ya0.w};
        unsigned bu[4] = {yb0.x, yb0.y, yb0.z, yb0.w};
        #pragma unroll
        for (int i2 = 0; i2 < 4; ++i2) {
            int na = n8 * 8 + 2 * i2, nb = na + 1;
            Bs[0][na * 16 + (fp ^ (((na >> 2) & 3) << 2))] = (au[i2] & 0xFFFFu) | (bu[i2] << 16);
            Bs[0][nb * 16 + (fp ^ (((nb >> 2) & 3) << 2))] = (au[i2] >> 16) | (bu[i2] & 0xFFFF0000u);
        }
    }
    __syncthreads();

    for (int kt = 0; kt < 15; ++kt) {
        int cur = kt & 1, nxt = cur ^ 1;
        int k1 = (kt + 1) * 32;
        // issue A(kt+1) and B(kt+2); both consumed a full step later
        load_lds16(Wg + (h0 + r) * 512 + k1 + qd * 8, &As[nxt][t * 8]);
        uint4 za2, zb2;
        if (kt < 14) {
            int k2 = (kt + 2) * 32;
            za2 = *(const uint4*)(ybase + (size_t)k2 * L_);
            zb2 = *(const uint4*)(ybase + (size_t)(k2 + 1) * L_);
        }

        short8 af[2], bf[4];
        #pragma unroll
        for (int mt = 0; mt < 2; ++mt)
            af[mt] = *(const short8*)&As[cur][(m_off + mt * 16 + ln) * 32 + quad * 8];
        #pragma unroll
        for (int nt = 0; nt < 4; ++nt) {
            int n = n_off + nt * 16 + ln;
            bf[nt] = *(const short8*)&Bs[cur][n * 16 + ((quad * 4) ^ (((n >> 2) & 3) << 2))];
        }
        #pragma unroll
        for (int mt = 0; mt < 2; ++mt)
            #pragma unroll
            for (int nt = 0; nt < 4; ++nt)
                acc[mt][nt] = __builtin_amdgcn_mfma_f32_16x16x32_bf16(
                    af[mt], bf[nt], acc[mt][nt], 0, 0, 0);
        __builtin_amdgcn_sched_barrier(0);   // keep B-write below the MFMA cluster

        {   // write Bs[kt+1] from regs loaded LAST step (vmcnt wait ~0)
            unsigned au[4] = {za1.x, za1.y, za1.z, za1.w};
            unsigned bu[4] = {zb1.x, zb1.y, zb1.z, zb1.w};
            #pragma unroll
            for (int i2 = 0; i2 < 4; ++i2) {
                int na = n8 * 8 + 2 * i2, nb = na + 1;
                Bs[nxt][na * 16 + (fp ^ (((na >> 2) & 3) << 2))] = (au[i2] & 0xFFFFu) | (bu[i2] << 16);
                Bs[nxt][nb * 16 + (fp ^ (((nb >> 2) & 3) << 2))] = (au[i2] >> 16) | (bu[i2] & 0xFFFF0000u);
            }
        }
        za1 = za2; zb1 = zb2;               // rotate pipeline regs
        __syncthreads();
    }
    {   // tail: kt = 15, buffer 1, compute only
        short8 af[2], bf[4];
        #pragma unroll
        for (int mt = 0; mt < 2; ++mt)
            af[mt] = *(const short8*)&As[1][(m_off + mt * 16 + ln) * 32 + quad * 8];
        #pragma unroll
        for (int nt = 0; nt < 4; ++nt) {
            int n = n_off + nt * 16 + ln;
            bf[nt] = *(const short8*)&Bs[1][n * 16 + ((quad * 4) ^ (((n >> 2) & 3) << 2))];
        }
        #pragma unroll
        for (int mt = 0; mt < 2; ++mt)
            #pragma unroll
            for (int nt = 0; nt < 4; ++nt)
                acc[mt][nt] = __builtin_amdgcn_mfma_f32_16x16x32_bf16(
                    af[mt], bf[nt], acc[mt][nt], 0, 0, 0);
    }

    #pragma unroll
    for (int mt = 0; mt < 2; ++mt) {
        #pragma unroll
        for (int nt = 0; nt < 4; ++nt) {
            int hh = h0 + m_off + mt * 16 + quad * 4;
            int ll = l0 + n_off + nt * 16 + ln;
            #pragma unroll
            for (int r2 = 0; r2 < 4; ++r2)
                out[((size_t)(b * H_ + hh + r2)) * L_ + ll] = acc[mt][nt][r2] + bias[hh + r2];
        }
    }
}

extern "C" void kernel_launch(void* const* d_in, const int* in_sizes, int n_in,
                              void* d_out, int out_size, void* d_ws, size_t ws_size,
                              hipStream_t stream) {
    const float* u    = (const float*)d_in[0];
    const float* a    = (const float*)d_in[1];
    const float* th   = (const float*)d_in[2];
    const float* bb   = (const float*)d_in[3];
    const float* cc   = (const float*)d_in[4];
    const float* x0   = (const float*)d_in[5];
    const float* Dp   = (const float*)d_in[6];
    const float* W    = (const float*)d_in[7];
    const float* bias = (const float*)d_in[8];
    float* out = (float*)d_out;
    char* ws = (char*)d_ws;

    // layout: FKf 4M @0 | y 16M @20M | Wb 0.5M @36M | AB 2M @37M |
    //         CB 3M @39M | WPh fp16 384KB @42M
    unsigned*       FKf = (unsigned*)ws;
    __hip_bfloat16* y   = (__hip_bfloat16*)(ws + (20ull << 20));
    __hip_bfloat16* Wb  = (__hip_bfloat16*)(ws + (36ull << 20));
    _Float16*       AB  = (_Float16*)(ws + (37ull << 20));
    _Float16*       CB  = (_Float16*)(ws + (39ull << 20));
    _Float16*       WPh = (_Float16*)(ws + (42ull << 20));

    hipLaunchKernelGGL(fkprep_kernel,     dim3(H_),        dim3(256), 0, stream,
                       a, th, bb, cc, x0, W, Wb, FKf, AB, CB, WPh);
    hipLaunchKernelGGL(scan_mfma_kernel,  dim3(H_, B_/2),  dim3(256), 0, stream,
                       u, AB, CB, (const unsigned*)WPh, Dp, FKf, y);
    hipLaunchKernelGGL(gemm_kernel,       dim3(16, 8, 8),  dim3(256), 0, stream,
                       Wb, y, bias, out);
}